// Round 4
// baseline (420.541 us; speedup 1.0000x reference)
//
#include <hip/hip_runtime.h>

#define N_TOK 262144
#define D_FEAT 128
#define C_CLS 64
#define NBLOCKS 512
#define NTHREADS 256            // 4 waves
#define ROWS_PER_BLOCK 512      // N_TOK / NBLOCKS
#define ROWS_PER_WAVE 128       // 8 tiles of 16 rows
#define NTILES 8
#define SEG_WORDS (D_FEAT * C_CLS)          // 8192
#define WS_SEG_BYTES ((size_t)NBLOCKS * SEG_WORDS * 4)

typedef __attribute__((ext_vector_type(8))) short bf16x8;
typedef __attribute__((ext_vector_type(4))) float f32x4;

__device__ __forceinline__ unsigned short f2bf(float x) {
    unsigned u = __float_as_uint(x);
    u += 0x7FFFu + ((u >> 16) & 1u);   // RTNE
    return (unsigned short)(u >> 16);
}

__device__ __forceinline__ bf16x8 pack8(f32x4 a, f32x4 b) {
    bf16x8 t;
    t[0] = (short)f2bf(a[0]); t[1] = (short)f2bf(a[1]);
    t[2] = (short)f2bf(a[2]); t[3] = (short)f2bf(a[3]);
    t[4] = (short)f2bf(b[0]); t[5] = (short)f2bf(b[1]);
    t[6] = (short)f2bf(b[2]); t[7] = (short)f2bf(b[3]);
    return t;
}

__device__ __forceinline__ float sq4(f32x4 v) {
    return v[0]*v[0] + v[1]*v[1] + v[2]*v[2] + v[3]*v[3];
}

// async global -> LDS, 16B per lane (global addr per-lane, LDS base wave-uniform)
__device__ __forceinline__ void load_lds16(const float* g, float* l) {
    __builtin_amdgcn_global_load_lds(
        (const __attribute__((address_space(1))) void*)g,
        (__attribute__((address_space(3))) void*)l, 16, 0, 0);
}

// seg swizzle: row's 4 k-quads land in 4 different banks
__device__ __forceinline__ int seg_idx(int k, int c) {
    return k * C_CLS + (c ^ (((k >> 3) & 3) << 3));
}

__global__ __launch_bounds__(NTHREADS, 2) void center_main(
    const float* __restrict__ f, const int* __restrict__ label,
    const float* __restrict__ centers, float* __restrict__ dist_out,
    float* __restrict__ ws_loss, float* __restrict__ ws_seg, int use_partials)
{
    __shared__ float seg[SEG_WORDS];       // 32 KB, [k][c^swz]
    __shared__ float stage[4][16 * 128];   // 4 waves x 8 KB tile buffers = 32 KB

    const int tid  = threadIdx.x;
    const int lane = tid & 63;
    const int w    = tid >> 6;      // wave 0..3
    const int qk   = lane >> 4;     // k-quad 0..3
    const int ln   = lane & 15;

    for (int i = tid; i < SEG_WORDS; i += NTHREADS) seg[i] = 0.f;

    // ---- B fragments + column norms, per wave, registers only ----
    // lane ln holds column n = 4*ln + ct, k = qk*8 + j + ks*32
    bf16x8 bfr[4][4];
    float  c2r[4];
    #pragma unroll
    for (int ct = 0; ct < 4; ++ct) {
        const float* bp = centers + (ln * 4 + ct) * D_FEAT + qk * 8;
        float c2p = 0.f;
        #pragma unroll
        for (int ks = 0; ks < 4; ++ks) {
            f32x4 v0 = *(const f32x4*)(bp + ks * 32);
            f32x4 v1 = *(const f32x4*)(bp + ks * 32 + 4);
            c2p += sq4(v0) + sq4(v1);
            bfr[ct][ks] = pack8(v0, v1);
        }
        c2p += __shfl_xor(c2p, 16);
        c2p += __shfl_xor(c2p, 32);
        c2r[ct] = c2p;              // full sum in all 4 quads of this ln
    }
    __syncthreads();                // seg zeroed before any atomics

    const int rowbase = blockIdx.x * ROWS_PER_BLOCK + w * ROWS_PER_WAVE;
    float* mybuf = stage[w];
    float lossa = 0.f;

    #pragma unroll 1
    for (int t = 0; t < NTILES; ++t) {
        const int base = rowbase + t * 16;

        const int lb = label[base + ln];        // row ln's label (16 distinct, 1 txn)

        // ---- DMA 16 rows (8 KB) into this wave's buffer ----
        #pragma unroll
        for (int i = 0; i < 8; ++i)
            load_lds16(f + (size_t)(base + 2 * i) * D_FEAT + lane * 4,
                       &mybuf[i * 256]);
        __builtin_amdgcn_s_waitcnt(0x0f70);     // vmcnt(0): DMA (and lb) complete

        // ---- read A-frag data from LDS; pack; row norm ----
        const float* rp = &mybuf[ln * D_FEAT + qk * 8];
        f32x4 raw[8];
        #pragma unroll
        for (int ks = 0; ks < 4; ++ks) {
            raw[2 * ks]     = *(const f32x4*)(rp + ks * 32);
            raw[2 * ks + 1] = *(const f32x4*)(rp + ks * 32 + 4);
        }
        bf16x8 afr[4];
        float s2 = 0.f;
        #pragma unroll
        for (int ks = 0; ks < 4; ++ks) {
            s2 += sq4(raw[2 * ks]) + sq4(raw[2 * ks + 1]);
            afr[ks] = pack8(raw[2 * ks], raw[2 * ks + 1]);
        }
        s2 += __shfl_xor(s2, 16);
        s2 += __shfl_xor(s2, 32);               // full ||row ln||^2 in all quads

        // ---- segment sums (LDS atomics, quad-spread banks) ----
        {
            const float* rf = (const float*)raw;
            #pragma unroll
            for (int ks = 0; ks < 4; ++ks)
                #pragma unroll
                for (int j = 0; j < 8; ++j) {
                    const int k = ks * 32 + qk * 8 + j;
                    atomicAdd(&seg[seg_idx(k, lb)], rf[ks * 8 + j]);
                }
        }

        // ---- MFMA ----
        f32x4 acc[4];
        #pragma unroll
        for (int ct = 0; ct < 4; ++ct) {
            f32x4 a = {0.f, 0.f, 0.f, 0.f};
            #pragma unroll
            for (int ks = 0; ks < 4; ++ks)
                a = __builtin_amdgcn_mfma_f32_16x16x32_bf16(afr[ks], bfr[ct][ks], a, 0, 0, 0);
            acc[ct] = a;
        }

        // ---- epilogue: dist (coalesced f32x4 NT) + loss gather ----
        #pragma unroll
        for (int v = 0; v < 4; ++v) {
            const int rl  = qk * 4 + v;          // local row of acc element v
            const float fv = __shfl(s2, rl);     // lane rl holds row rl's norm
            const int  lb2 = __shfl(lb, rl);
            f32x4 o;
            o[0] = fv + c2r[0] - 2.f * acc[0][v];
            o[1] = fv + c2r[1] - 2.f * acc[1][v];
            o[2] = fv + c2r[2] - 2.f * acc[2][v];
            o[3] = fv + c2r[3] - 2.f * acc[3][v];
            if ((lb2 >> 2) == ln) {
                const int sub = lb2 & 3;
                lossa += sub < 2 ? (sub == 0 ? o[0] : o[1])
                                 : (sub == 2 ? o[2] : o[3]);
            }
            __builtin_nontemporal_store(o,
                (f32x4*)(dist_out + (size_t)(base + rl) * C_CLS + ln * 4));
        }
    }

    // ---- flush: coalesced per-block partial store (or atomic fallback) ----
    __syncthreads();
    if (use_partials) {
        float* dst = ws_seg + (size_t)blockIdx.x * SEG_WORDS;
        for (int i = tid; i < SEG_WORDS; i += NTHREADS)
            __builtin_nontemporal_store(seg[i], dst + i);
    } else {
        for (int i = tid; i < SEG_WORDS; i += NTHREADS)
            unsafeAtomicAdd(&ws_seg[i], seg[i]);
    }
    #pragma unroll
    for (int off = 32; off; off >>= 1) lossa += __shfl_xor(lossa, off);
    if (lane == 0) unsafeAtomicAdd(ws_loss, lossa);
}

// label histogram: 256 blocks x 256 thr, int4 reads, LDS hist, 64 atomics/block
__global__ void count_k(const int* __restrict__ label, unsigned* __restrict__ ws_cnt)
{
    __shared__ unsigned h[C_CLS];
    const int tid = threadIdx.x;
    if (tid < C_CLS) h[tid] = 0u;
    __syncthreads();
    const int4 l4 = ((const int4*)label)[blockIdx.x * 256 + tid];
    atomicAdd(&h[l4.x], 1u); atomicAdd(&h[l4.y], 1u);
    atomicAdd(&h[l4.z], 1u); atomicAdd(&h[l4.w], 1u);
    __syncthreads();
    if (tid < C_CLS) atomicAdd(&ws_cnt[tid], h[tid]);
}

__global__ void center_fin(const float* __restrict__ centers,
                           const float* __restrict__ ws_loss,
                           const unsigned* __restrict__ ws_cnt,
                           const float* __restrict__ ws_seg,
                           float* __restrict__ out, int use_partials)
{
    const int j = blockIdx.x * 256 + threadIdx.x;   // seg-layout index
    if (j >= SEG_WORDS) return;
    const int k  = j >> 6;
    const int cs = j & 63;
    const int c  = cs ^ (((k >> 3) & 3) << 3);      // unswizzle -> logical class

    float s;
    if (use_partials) {
        float a0 = 0.f, a1 = 0.f, a2 = 0.f, a3 = 0.f;
        #pragma unroll 4
        for (int p = 0; p < NBLOCKS; p += 4) {
            a0 += ws_seg[(size_t)(p + 0) * SEG_WORDS + j];
            a1 += ws_seg[(size_t)(p + 1) * SEG_WORDS + j];
            a2 += ws_seg[(size_t)(p + 2) * SEG_WORDS + j];
            a3 += ws_seg[(size_t)(p + 3) * SEG_WORDS + j];
        }
        s = (a0 + a1) + (a2 + a3);
    } else {
        s = ws_seg[j];
    }
    const unsigned cnt = ws_cnt[c];
    const float denom = (float)(cnt > 1u ? cnt : 1u);
    out[1 + c * D_FEAT + k] = ((float)cnt * centers[c * D_FEAT + k] - s) / denom;
    if (j == 0) out[0] = ws_loss[0] / ((float)N_TOK * (float)D_FEAT);
}

extern "C" void kernel_launch(void* const* d_in, const int* in_sizes, int n_in,
                              void* d_out, int out_size, void* d_ws, size_t ws_size,
                              hipStream_t stream)
{
    const float* f       = (const float*)d_in[0];
    const int*   lbl     = (const int*)d_in[1];
    const float* centers = (const float*)d_in[2];
    float* out = (float*)d_out;

    float*    ws_loss = (float*)d_ws;
    unsigned* ws_cnt  = (unsigned*)((char*)d_ws + 256);
    float*    ws_seg  = (float*)((char*)d_ws + 1024);

    const int use_partials = (ws_size >= 1024 + WS_SEG_BYTES) ? 1 : 0;

    // zero loss/cnt always, plus seg accumulator region (covers atomic fallback)
    (void)hipMemsetAsync(d_ws, 0, 1024 + SEG_WORDS * 4, stream);

    count_k<<<256, 256, 0, stream>>>(lbl, ws_cnt);

    float* dist_out = out + 1 + C_CLS * D_FEAT;
    center_main<<<NBLOCKS, NTHREADS, 0, stream>>>(f, lbl, centers, dist_out,
                                                  ws_loss, ws_seg, use_partials);
    center_fin<<<32, 256, 0, stream>>>(centers, ws_loss, ws_cnt, ws_seg, out,
                                       use_partials);
}